// Round 7
// baseline (228.819 us; speedup 1.0000x reference)
//
#include <hip/hip_runtime.h>
#include <hip/hip_bf16.h>
#include <cstdint>
#include <cstddef>

#define E_ 1024
#define H_ 16
#define D_ 64
#define B_ 2
#define S_ 2048
#define T_ 4096   // B_*S_
#define NQ_ 3072  // 3*E_

typedef __bf16 bf16_t;
typedef bf16_t bf16x8 __attribute__((ext_vector_type(8)));
typedef float f32x4 __attribute__((ext_vector_type(4)));

static __device__ __forceinline__ unsigned short f2bf(float f) {
    __hip_bfloat16 h = __float2bfloat16(f);
    return __builtin_bit_cast(unsigned short, h);
}
static __device__ __forceinline__ unsigned pack2(float a, float b) {
    return (unsigned)f2bf(a) | ((unsigned)f2bf(b) << 16);
}
static __device__ __forceinline__ bf16x8 ld_frag(const unsigned short* p) {
    uint4 u = *reinterpret_cast<const uint4*>(p);
    return __builtin_bit_cast(bf16x8, u);
}
// async global->LDS, 16B per lane. LDS dest must be wave-uniform base + lane*16.
static __device__ __forceinline__ void cp16(unsigned short* lds, const unsigned short* g) {
    __builtin_amdgcn_global_load_lds(
        (const __attribute__((address_space(1))) unsigned int*)g,
        (__attribute__((address_space(3))) unsigned int*)lds, 16, 0, 0);
}
static __device__ __forceinline__ f32x4 mfma16(bf16x8 a, bf16x8 b, f32x4 c) {
    return __builtin_amdgcn_mfma_f32_16x16x32_bf16(a, b, c, 0, 0, 0);
}
// {lo16 = hi(a), hi16 = hi(b)} : truncating bf16 pack in ONE v_perm_b32
static __device__ __forceinline__ unsigned pack2_trunc(unsigned a_bits, unsigned b_bits) {
    return __builtin_amdgcn_perm(b_bits, a_bits, 0x07060302u);
}

// GEMM operand image, FRAGMENT ORDER: matrix X[R][Kdim] as 128x32 tiles.
// tile = (r>>7)*(Kdim>>5) + (k>>5); chunk p = ((r&127)>>4)*64 + ((k&31)>>3)*16 + (r&15)
// element offset = tile*4096 + p*8 + (k&7).  Consumer frag read = base + lane*16B.

// ---------------- fused pre-pass: cvt hidden + transpose both weights ----------------
__global__ __launch_bounds__(256) void k_pre(const float* __restrict__ hs,
                                             const float* __restrict__ w1,
                                             const float* __restrict__ w2,
                                             unsigned short* __restrict__ hb,
                                             unsigned short* __restrict__ w1t,
                                             unsigned short* __restrict__ w2t) {
    __shared__ float tsh[32][33];
    int id = blockIdx.x, t = threadIdx.x;
    if (id < 4096) {
        // hidden fp32 -> bf16 A-image (fragment order)
        int i = (id * 256 + t) * 4;
        float4 v = *reinterpret_cast<const float4*>(hs + i);
        int tok = i >> 10, e = i & 1023;
        int p = ((tok & 127) >> 4) * 64 + ((e & 31) >> 3) * 16 + (tok & 15);
        size_t off = ((size_t)(tok >> 7) * 32 + (e >> 5)) * 4096 + p * 8 + (e & 7);
        uint2 o;
        o.x = pack2(v.x, v.y);
        o.y = pack2(v.z, v.w);
        *reinterpret_cast<uint2*>(hb + off) = o;
    } else {
        // weight transpose fp32 [K][N] -> bf16 B-image (fragment order)
        const float* in;
        unsigned short* out;
        int bx, by, N, nkt;
        if (id < 4096 + 3072) {
            int bid = id - 4096;
            in = w1; out = w1t; N = NQ_; nkt = 32;
            bx = bid % 96; by = bid / 96;
        } else {
            int bid = id - 7168;
            in = w2; out = w2t; N = E_; nkt = 32;
            bx = bid & 31; by = bid >> 5;
        }
        int n0 = bx * 32, k0 = by * 32;
        int tx = t & 31, ty = t >> 5;
        for (int j = 0; j < 4; j++) {
            int r = ty + j * 8;
            tsh[r][tx] = in[(size_t)(k0 + r) * N + n0 + tx];
        }
        __syncthreads();
        for (int j = 0; j < 4; j++) {
            int r = ty + j * 8;
            int nn = n0 + r;
            int p = ((nn & 127) >> 4) * 64 + (tx >> 3) * 16 + (nn & 15);
            size_t off = ((size_t)(nn >> 7) * nkt + (k0 >> 5)) * 4096 + p * 8 + (tx & 7);
            out[off] = f2bf(tsh[tx][r]);
        }
    }
}

// ---------------- shared 128x128 GEMM core: dbuf, single barrier/iter ----------------
// Staging: pure linear copy. LDS tiles in fragment order -> lane-linear b128 reads.
template <bool TR>
static __device__ __forceinline__ void gemm_tile_128(
    const unsigned short* __restrict__ At,
    const unsigned short* __restrict__ Bt,
    int nkt, int m0, int n0,
    unsigned short* As, unsigned short* Bs,   // each 2*4096 shorts (dbuf)
    f32x4 acc[4][4])
{
    const int t = threadIdx.x;
    const int w = t >> 6, lane = t & 63;
    const int wmg = (w >> 1) * 4, wng = (w & 1) * 4;
    for (int mt = 0; mt < 4; mt++)
        for (int nt = 0; nt < 4; nt++)
            acc[mt][nt] = (f32x4){0.f, 0.f, 0.f, 0.f};

    const unsigned short* ag = At + (size_t)(m0 >> 7) * nkt * 4096 + t * 8;
    const unsigned short* bg = Bt + (size_t)(n0 >> 7) * nkt * 4096 + t * 8;

    // prologue: stage k-tile 0 into buffer 0
    cp16(&As[t * 8], ag);  cp16(&As[(t + 256) * 8], ag + 2048);
    cp16(&Bs[t * 8], bg);  cp16(&Bs[(t + 256) * 8], bg + 2048);
    ag += 4096; bg += 4096;
    __syncthreads();

    for (int kt = 0; kt < nkt; kt++) {
        unsigned short* Ap = As + (kt & 1) * 4096;
        unsigned short* Bp = Bs + (kt & 1) * 4096;
        if (kt + 1 < nkt) {
            unsigned short* An = As + ((kt + 1) & 1) * 4096;
            unsigned short* Bn = Bs + ((kt + 1) & 1) * 4096;
            cp16(&An[t * 8], ag);  cp16(&An[(t + 256) * 8], ag + 2048);
            cp16(&Bn[t * 8], bg);  cp16(&Bn[(t + 256) * 8], bg + 2048);
            ag += 4096; bg += 4096;
        }
        bf16x8 af[4], bfr[4];
        for (int mt = 0; mt < 4; mt++) af[mt]  = ld_frag(&Ap[((wmg + mt) * 64 + lane) * 8]);
        for (int nt = 0; nt < 4; nt++) bfr[nt] = ld_frag(&Bp[((wng + nt) * 64 + lane) * 8]);
        for (int mt = 0; mt < 4; mt++)
            for (int nt = 0; nt < 4; nt++)
                acc[mt][nt] = TR ? mfma16(bfr[nt], af[mt], acc[mt][nt])
                                 : mfma16(af[mt], bfr[nt], acc[mt][nt]);
        __syncthreads();   // drains next-tile staging (overlapped with compute above)
    }
}

// ---------------- QKV GEMM + bias + split-heads epilogue (writes K/V attn images) ----
__global__ __launch_bounds__(256) void k_qkv(
    const unsigned short* __restrict__ Ab, const unsigned short* __restrict__ Wt,
    const float* __restrict__ bias,
    unsigned short* __restrict__ Qb, unsigned short* __restrict__ Kimg,
    unsigned short* __restrict__ Vimg)
{
    __shared__ __attribute__((aligned(16))) unsigned short As[2 * 4096];
    __shared__ __attribute__((aligned(16))) unsigned short Bs[2 * 4096];
    f32x4 acc[4][4];
    int m0 = blockIdx.x * 128, n0 = blockIdx.y * 128;
    int sector = (n0 >> 10);
    if (sector == 2) gemm_tile_128<false>(Ab, Wt, E_ / 32, m0, n0, As, Bs, acc);
    else             gemm_tile_128<true >(Ab, Wt, E_ / 32, m0, n0, As, Bs, acc);

    int t = threadIdx.x, w = t >> 6, lane = t & 63, lr = lane & 15, lq = lane >> 4;
    int wm = (w >> 1) * 64, wn = (w & 1) * 64;

    if (sector == 2) {
        // V image (normal C): 4 consecutive keys/lane -> uint2
        for (int nt = 0; nt < 4; nt++) {
            int n = n0 + wn + nt * 16 + lr;
            float bv = bias[n];
            int nn = n & 1023, hh = nn >> 6, d = nn & 63;
            for (int mt = 0; mt < 4; mt++) {
                int tok0 = m0 + wm + mt * 16 + lq * 4;
                int bb = tok0 >> 11, s0 = tok0 & 2047;
                size_t headOff = (size_t)(bb * H_ + hh) * (S_ * D_);
                int tile = s0 >> 7, j = s0 & 127, stripe = j >> 5, lq_ = (j >> 3) & 3, pos = j & 7;
                int dt = d >> 4;
                size_t off = headOff + (size_t)tile * 8192 +
                    ((size_t)((stripe * 4 + dt) * 64 + lq_ * 16 + (d & 15))) * 8 + pos;
                uint2 u;
                u.x = pack2(acc[mt][nt][0] + bv, acc[mt][nt][1] + bv);
                u.y = pack2(acc[mt][nt][2] + bv, acc[mt][nt][3] + bv);
                *reinterpret_cast<uint2*>(Vimg + off) = u;
            }
        }
    } else {
        // Q / K (C^T): 4 consecutive d per lane -> uint2
        for (int nt = 0; nt < 4; nt++) {
            int n = n0 + wn + nt * 16 + lq * 4;
            float4 bv4 = *reinterpret_cast<const float4*>(&bias[n]);
            int nn = n & 1023, hh = nn >> 6, d0 = nn & 63;
            for (int mt = 0; mt < 4; mt++) {
                int tok = m0 + wm + mt * 16 + lr;
                int bb = tok >> 11, s = tok & 2047;
                size_t headOff = (size_t)(bb * H_ + hh) * (S_ * D_);
                float v0 = acc[mt][nt][0] + bv4.x, v1 = acc[mt][nt][1] + bv4.y;
                float v2 = acc[mt][nt][2] + bv4.z, v3 = acc[mt][nt][3] + bv4.w;
                if (sector == 0) {
                    const float c = 0.18033688011112042f;   // log2(e)/sqrt(D)
                    uint2 u;
                    u.x = pack2(v0 * c, v1 * c);
                    u.y = pack2(v2 * c, v3 * c);
                    *reinterpret_cast<uint2*>(Qb + headOff + (size_t)s * 64 + d0) = u;
                } else {
                    int dc = d0 >> 5, lq_ = (d0 >> 3) & 3, pos = d0 & 7;
                    int tile = s >> 7, j = s & 127, stripe = j >> 5, jj = j & 31;
                    int h2 = (jj >> 2) & 1, slot = ((jj >> 3) << 2) | (jj & 3);
                    size_t off = headOff + (size_t)tile * 8192 +
                        ((size_t)(((stripe * 2 + h2) * 2 + dc) * 64 + lq_ * 16 + slot)) * 8 + pos;
                    uint2 u;
                    u.x = pack2(v0, v1);
                    u.y = pack2(v2, v3);
                    *reinterpret_cast<uint2*>(Kimg + off) = u;
                }
            }
        }
    }
}

// ---------------- flash attention: dbuf, single barrier/iter, register P ----------
__global__ __launch_bounds__(256) void k_attn(
    const unsigned short* __restrict__ Qb, const unsigned short* __restrict__ Kimg,
    const unsigned short* __restrict__ Vimg, unsigned short* __restrict__ Ao)
{
    // shorts: Ks0 [0,8192) Ks1 [8192,16384) Vt0 [16384,24576) Vt1 [24576,32768)
    __shared__ __attribute__((aligned(16))) unsigned short smem[32768];   // 64 KB
    float* Lred = (float*)(smem + 28672); // inside Vt1, written only after final barrier
    float* Ored = (float*)smem;           // aliases Ks after final barrier: [64 q][68]

    const int t = threadIdx.x, w = t >> 6, lane = t & 63, lr = lane & 15, lq = lane >> 4;

    // XCD swizzle: all 32 q-blocks of one head share an XCD (id%8 round-robin)
    const int id = blockIdx.x;
    const int xcd = id & 7, slot = id >> 3;
    const int qblk = slot & 31;
    const int hb = ((slot >> 5) << 3) | xcd;
    const int h = hb & 15, b = hb >> 4;

    const size_t head = (size_t)(b * H_ + h) * (S_ * D_);
    const unsigned short* Qh = Qb + head;
    const unsigned short* kg = Kimg + head + t * 8;
    const unsigned short* vg = Vimg + head + t * 8;
    const int q0 = qblk * 64;

    // Q fragments (B-operand), scale*log2e pre-folded
    bf16x8 qf[4][2];
    for (int qt = 0; qt < 4; qt++)
        for (int dc = 0; dc < 2; dc++)
            qf[qt][dc] = ld_frag(&Qh[(size_t)(q0 + qt * 16 + lr) * 64 + dc * 32 + lq * 8]);

    bf16x8 ones;
    {
        uint4 u = {0x3f803f80u, 0x3f803f80u, 0x3f803f80u, 0x3f803f80u};
        ones = __builtin_bit_cast(bf16x8, u);
    }

    f32x4 o[4][4];   // [qt][dt]: O^T partial
    f32x4 oL[4];     // denominator partials
    for (int qt = 0; qt < 4; qt++) {
        oL[qt] = (f32x4){0.f, 0.f, 0.f, 0.f};
        for (int dt = 0; dt < 4; dt++)
            o[qt][dt] = (f32x4){0.f, 0.f, 0.f, 0.f};
    }

    // prologue: stage tile 0 into buffer 0
    {
        unsigned short* K0 = smem;
        unsigned short* V0 = smem + 16384;
        cp16(&K0[t * 8], kg);                cp16(&K0[(t + 256) * 8], kg + 2048);
        cp16(&K0[(t + 512) * 8], kg + 4096); cp16(&K0[(t + 768) * 8], kg + 6144);
        cp16(&V0[t * 8], vg);                cp16(&V0[(t + 256) * 8], vg + 2048);
        cp16(&V0[(t + 512) * 8], vg + 4096); cp16(&V0[(t + 768) * 8], vg + 6144);
        kg += 8192; vg += 8192;
    }
    __syncthreads();

    for (int it = 0; it < S_ / 128; it++) {
        unsigned short* Ks = smem + (it & 1) * 8192;
        unsigned short* Vt = smem + 16384 + (it & 1) * 8192;
        if (it + 1 < S_ / 128) {
            unsigned short* Kn = smem + ((it + 1) & 1) * 8192;
            unsigned short* Vn = smem + 16384 + ((it + 1) & 1) * 8192;
            cp16(&Kn[t * 8], kg);                cp16(&Kn[(t + 256) * 8], kg + 2048);
            cp16(&Kn[(t + 512) * 8], kg + 4096); cp16(&Kn[(t + 768) * 8], kg + 6144);
            cp16(&Vn[t * 8], vg);                cp16(&Vn[(t + 256) * 8], vg + 2048);
            cp16(&Vn[(t + 512) * 8], vg + 4096); cp16(&Vn[(t + 768) * 8], vg + 6144);
            kg += 8192; vg += 8192;
        }

        // QK^T (log2 domain) for this wave's 32-key stripe: permuted subtiles h2=0,1
        f32x4 z[2][4];
#pragma unroll
        for (int h2 = 0; h2 < 2; h2++) {
            bf16x8 kf0 = ld_frag(&Ks[((w * 4 + h2 * 2 + 0) * 64 + lane) * 8]);
            bf16x8 kf1 = ld_frag(&Ks[((w * 4 + h2 * 2 + 1) * 64 + lane) * 8]);
            for (int qt = 0; qt < 4; qt++) {
                f32x4 zz = (f32x4){0.f, 0.f, 0.f, 0.f};
                zz = mfma16(kf0, qf[qt][0], zz);
                zz = mfma16(kf1, qf[qt][1], zz);
                z[h2][qt] = zz;
            }
        }
        // raw v_exp_f32 -> truncating v_perm pack -> P^T B-fragment in registers
        bf16x8 pb[4];
#pragma unroll
        for (int qt = 0; qt < 4; qt++) {
            unsigned e0 = __builtin_bit_cast(unsigned, __builtin_amdgcn_exp2f(z[0][qt][0]));
            unsigned e1 = __builtin_bit_cast(unsigned, __builtin_amdgcn_exp2f(z[0][qt][1]));
            unsigned e2 = __builtin_bit_cast(unsigned, __builtin_amdgcn_exp2f(z[0][qt][2]));
            unsigned e3 = __builtin_bit_cast(unsigned, __builtin_amdgcn_exp2f(z[0][qt][3]));
            unsigned e4 = __builtin_bit_cast(unsigned, __builtin_amdgcn_exp2f(z[1][qt][0]));
            unsigned e5 = __builtin_bit_cast(unsigned, __builtin_amdgcn_exp2f(z[1][qt][1]));
            unsigned e6 = __builtin_bit_cast(unsigned, __builtin_amdgcn_exp2f(z[1][qt][2]));
            unsigned e7 = __builtin_bit_cast(unsigned, __builtin_amdgcn_exp2f(z[1][qt][3]));
            uint4 u;
            u.x = pack2_trunc(e0, e1);
            u.y = pack2_trunc(e2, e3);
            u.z = pack2_trunc(e4, e5);
            u.w = pack2_trunc(e6, e7);
            pb[qt] = __builtin_bit_cast(bf16x8, u);
        }
        // denominator via MFMA (exactly consistent with PV's truncated P)
        for (int qt = 0; qt < 4; qt++)
            oL[qt] = mfma16(ones, pb[qt], oL[qt]);
        // PV: O^T += V^T * P^T
        bf16x8 vf[4];
#pragma unroll
        for (int dt = 0; dt < 4; dt++)
            vf[dt] = ld_frag(&Vt[((w * 4 + dt) * 64 + lane) * 8]);
        for (int qt = 0; qt < 4; qt++)
            for (int dt = 0; dt < 4; dt++)
                o[qt][dt] = mfma16(vf[dt], pb[qt], o[qt][dt]);

        __syncthreads();   // drains next-tile staging (overlapped with the math above)
    }

    // publish per-wave denominator partials
    if (lq == 0)
        for (int qt = 0; qt < 4; qt++)
            Lred[w * 64 + qt * 16 + lr] = oL[qt][0];

    // cross-wave O reduction, float4 granularity
    for (int ww = 0; ww < 4; ww++) {
        if (w == ww) {
            for (int qt = 0; qt < 4; qt++)
                for (int dt = 0; dt < 4; dt++) {
                    int q = qt * 16 + lr, d = dt * 16 + lq * 4;
                    float4* p = reinterpret_cast<float4*>(&Ored[q * 68 + d]);
                    float4 vv = {o[qt][dt][0], o[qt][dt][1], o[qt][dt][2], o[qt][dt][3]};
                    if (ww == 0) *p = vv;
                    else {
                        float4 c = *p;
                        c.x += vv.x; c.y += vv.y; c.z += vv.z; c.w += vv.w;
                        *p = c;
                    }
                }
        }
        __syncthreads();
    }

    // output epilogue -> Ao fragment-order A-image; lane t: q = t>>2, 16 d at (t&3)*16
    {
        int q = t >> 2, dsg = (t & 3) * 16;
        float inv = 1.0f / (Lred[q] + Lred[64 + q] + Lred[128 + q] + Lred[192 + q]);
        const float* rp = &Ored[q * 68 + dsg];
        unsigned u[8];
        for (int j = 0; j < 8; j++)
            u[j] = pack2(rp[2 * j] * inv, rp[2 * j + 1] * inv);
        int tok = b * S_ + q0 + q, e0 = h * 64 + dsg;
        int p = ((tok & 127) >> 4) * 64 + ((e0 & 31) >> 3) * 16 + (tok & 15);
        size_t base = ((size_t)(tok >> 7) * 32 + (e0 >> 5)) * 4096;
        uint4 s0 = {u[0], u[1], u[2], u[3]};
        uint4 s1 = {u[4], u[5], u[6], u[7]};
        *reinterpret_cast<uint4*>(&Ao[base + p * 8]) = s0;
        *reinterpret_cast<uint4*>(&Ao[base + (p + 16) * 8]) = s1;
    }
}

// ---------------- output projection + bias -> fp32 out (C^T, float4 stores) ----------
__global__ __launch_bounds__(256) void k_proj(
    const unsigned short* __restrict__ Ab, const unsigned short* __restrict__ Wt,
    const float* __restrict__ bias, float* __restrict__ out)
{
    __shared__ __attribute__((aligned(16))) unsigned short As[2 * 4096];
    __shared__ __attribute__((aligned(16))) unsigned short Bs[2 * 4096];
    f32x4 acc[4][4];
    int m0 = blockIdx.x * 128, n0 = blockIdx.y * 128;
    gemm_tile_128<true>(Ab, Wt, E_ / 32, m0, n0, As, Bs, acc);

    int t = threadIdx.x, w = t >> 6, lane = t & 63, lr = lane & 15, lq = lane >> 4;
    int wm = (w >> 1) * 64, wn = (w & 1) * 64;
    for (int nt = 0; nt < 4; nt++) {
        int n = n0 + wn + nt * 16 + lq * 4;
        float4 bv4 = *reinterpret_cast<const float4*>(&bias[n]);
        for (int mt = 0; mt < 4; mt++) {
            int tok = m0 + wm + mt * 16 + lr;
            float4 vv = {acc[mt][nt][0] + bv4.x, acc[mt][nt][1] + bv4.y,
                         acc[mt][nt][2] + bv4.z, acc[mt][nt][3] + bv4.w};
            *reinterpret_cast<float4*>(&out[(size_t)tok * E_ + n]) = vv;
        }
    }
}

extern "C" void kernel_launch(void* const* d_in, const int* in_sizes, int n_in,
                              void* d_out, int out_size, void* d_ws, size_t ws_size,
                              hipStream_t stream) {
    const float* hs = (const float*)d_in[0];   // [2,2048,1024]
    const float* w1 = (const float*)d_in[1];   // [1024,3072]
    const float* b1 = (const float*)d_in[2];   // [3072]
    const float* w2 = (const float*)d_in[3];   // [1024,1024]
    const float* b2 = (const float*)d_in[4];   // [1024]
    float* out = (float*)d_out;

    char* ws = (char*)d_ws;
    unsigned short* hb  = (unsigned short*)(ws);                       // 8 MB hidden A-image
    unsigned short* w1t = (unsigned short*)(ws + (size_t)( 8 << 20));  // 6 MB Wqkv^T B-image
    unsigned short* w2t = (unsigned short*)(ws + (size_t)(14 << 20));  // 2 MB Wproj^T B-image
    unsigned short* Qb  = (unsigned short*)(ws + (size_t)(16 << 20));  // 8 MB [B,H,S,D] pre-scaled
    unsigned short* Kim = (unsigned short*)(ws + (size_t)(24 << 20));  // 8 MB K attn image
    unsigned short* Vim = (unsigned short*)(ws + (size_t)(32 << 20));  // 8 MB V attn image
    unsigned short* Ao  = (unsigned short*)(ws + (size_t)(40 << 20));  // 8 MB attn-out A-image

    k_pre<<<dim3(4096 + 3072 + 1024), dim3(256), 0, stream>>>(hs, w1, w2, hb, w1t, w2t);
    k_qkv<<<dim3(T_ / 128, NQ_ / 128), dim3(256), 0, stream>>>(hb, w1t, b1, Qb, Kim, Vim);
    k_attn<<<dim3(S_ / 64 * H_ * B_), dim3(256), 0, stream>>>(Qb, Kim, Vim, Ao);
    k_proj<<<dim3(T_ / 128, E_ / 128), dim3(256), 0, stream>>>(Ao, w2t, b2, out);
}